// Round 3
// baseline (343.819 us; speedup 1.0000x reference)
//
#include <hip/hip_runtime.h>
#include <hip/hip_cooperative_groups.h>
#include <stdint.h>
#include <float.h>

namespace cg = cooperative_groups;

#define NBINS 2048
#define NC 4            // LDS histogram copies, bin-interleaved
#define CAND_CAP 32768
#define NBLOCKS 256     // == CU count: guaranteed co-resident for cooperative launch
#define NTHREADS 1024

// ws layout (unsigned):
// [0, 2048)  coarse histogram (top 11 bits of abs bits)
// [2048]     candidate counter
// [2049]     minkey (ordered-uint encoding of global min)
// [2064, +CAND_CAP) candidate abs-bit patterns

__device__ __forceinline__ unsigned fkey(float f) {
    unsigned u = __float_as_uint(f);
    return (u & 0x80000000u) ? ~u : (u | 0x80000000u);
}

__global__ __launch_bounds__(NTHREADS, 4) void fused_kernel(
    const float* __restrict__ in, long long n, unsigned k,
    const float* __restrict__ min_val, const float* __restrict__ max_val,
    const int* __restrict__ num_flag,
    unsigned* __restrict__ ws, float* __restrict__ out) {
    __shared__ unsigned smem[NBINS * NC + 64];  // 32.25 KB, multi-purpose
    __shared__ unsigned wmin[NTHREADS / 64];
    __shared__ unsigned sstate[4];

    cg::grid_group grid = cg::this_grid();

    unsigned* hist = ws;
    unsigned* counter = ws + 2048;
    unsigned* minkey = ws + 2049;
    unsigned* cand = ws + 2064;

    long long gtid = (long long)blockIdx.x * blockDim.x + threadIdx.x;
    long long gstride = (long long)gridDim.x * blockDim.x;

    // ---- phase 0: zero global state (no memsets needed) ----
    for (long long i = gtid; i < NBINS; i += gstride) hist[i] = 0;
    if (gtid == 0) { *counter = 0; *minkey = 0xFFFFFFFFu; }

    // ---- phase 1: LDS histogram + local min (local work only) ----
    for (int i = threadIdx.x; i < NBINS * NC; i += blockDim.x) smem[i] = 0;
    __syncthreads();

    const unsigned c = threadIdx.x & (NC - 1);
    const float4* in4 = (const float4*)in;
    long long n4 = n >> 2;
    float mn = FLT_MAX;
    for (long long i = gtid; i < n4; i += gstride) {
        float4 v = in4[i];
        mn = fminf(mn, fminf(fminf(v.x, v.y), fminf(v.z, v.w)));
        unsigned ux = __float_as_uint(v.x) & 0x7FFFFFFFu;
        unsigned uy = __float_as_uint(v.y) & 0x7FFFFFFFu;
        unsigned uz = __float_as_uint(v.z) & 0x7FFFFFFFu;
        unsigned uw = __float_as_uint(v.w) & 0x7FFFFFFFu;
        atomicAdd(&smem[(ux >> 20) * NC + c], 1u);
        atomicAdd(&smem[(uy >> 20) * NC + c], 1u);
        atomicAdd(&smem[(uz >> 20) * NC + c], 1u);
        atomicAdd(&smem[(uw >> 20) * NC + c], 1u);
    }
    for (long long i = (n4 << 2) + gtid; i < n; i += gstride) {
        float v = in[i];
        mn = fminf(mn, v);
        atomicAdd(&smem[((__float_as_uint(v) & 0x7FFFFFFFu) >> 20) * NC + c], 1u);
    }
    __syncthreads();

    grid.sync();  // #1: all zeroing (and local hists) complete

    // ---- flush LDS hist to global; block-reduce min; atomicMin ----
    for (int b = threadIdx.x; b < NBINS; b += blockDim.x) {
        unsigned s = 0;
#pragma unroll
        for (int j = 0; j < NC; ++j) s += smem[b * NC + j];
        if (s) atomicAdd(&hist[b], s);
    }
    unsigned key = fkey(mn);
    for (int off = 32; off > 0; off >>= 1)
        key = min(key, (unsigned)__shfl_down((int)key, off));
    if ((threadIdx.x & 63) == 0) wmin[threadIdx.x >> 6] = key;
    __syncthreads();
    if (threadIdx.x == 0) {
        unsigned m = wmin[0];
        for (int w = 1; w < NTHREADS / 64; ++w) m = min(m, wmin[w]);
        atomicMin(minkey, m);
    }

    grid.sync();  // #2: global hist complete

    // ---- phase 2: per-block bucket select (redundant, identical result) ----
    if (threadIdx.x < 256) {
        unsigned s = 0;
        for (int j = 0; j < 8; ++j) s += hist[threadIdx.x * 8 + j];
        smem[threadIdx.x] = s;
    }
    __syncthreads();
    if (threadIdx.x == 0) {
        unsigned cum = 0;
        int seg = 0;
        for (; seg < 256; ++seg) {
            if (cum + smem[seg] >= k) break;
            cum += smem[seg];
        }
        int b = seg * 8;
        for (;; ++b) {
            unsigned cc = hist[b];
            if (cum + cc >= k) break;
            cum += cc;
        }
        sstate[0] = (unsigned)b;
        sstate[1] = k - cum;  // 1-indexed rank within bucket
    }
    __syncthreads();
    unsigned bsel = sstate[0];

    // ---- phase 3: compact candidates (input is L3-hot from phase 1) ----
    for (long long i = gtid; i < n4; i += gstride) {
        float4 v = in4[i];
        unsigned u[4];
        u[0] = __float_as_uint(v.x) & 0x7FFFFFFFu;
        u[1] = __float_as_uint(v.y) & 0x7FFFFFFFu;
        u[2] = __float_as_uint(v.z) & 0x7FFFFFFFu;
        u[3] = __float_as_uint(v.w) & 0x7FFFFFFFu;
#pragma unroll
        for (int j = 0; j < 4; ++j) {
            if ((u[j] >> 20) == bsel) {
                unsigned p = atomicAdd(counter, 1u);
                if (p < CAND_CAP) cand[p] = u[j];
            }
        }
    }
    for (long long i = (n4 << 2) + gtid; i < n; i += gstride) {
        unsigned u = __float_as_uint(in[i]) & 0x7FFFFFFFu;
        if ((u >> 20) == bsel) {
            unsigned p = atomicAdd(counter, 1u);
            if (p < CAND_CAP) cand[p] = u;
        }
    }

    grid.sync();  // #3: candidates + minkey complete

    // ---- phase 4: block 0 does the fine 2-level select + EMA update ----
    if (blockIdx.x != 0) return;

    unsigned* h = smem;           // 1024
    unsigned* part = smem + 1024; // 32
    unsigned m = min(*counter, (unsigned)CAND_CAP);
    unsigned r = sstate[1];

    // level 1: bits 19..10
    h[threadIdx.x] = 0;
    __syncthreads();
    for (unsigned i = threadIdx.x; i < m; i += blockDim.x)
        atomicAdd(&h[(cand[i] >> 10) & 1023u], 1u);
    __syncthreads();
    if (threadIdx.x < 32) {
        unsigned s = 0;
        for (int j = 0; j < 32; ++j) s += h[threadIdx.x * 32 + j];
        part[threadIdx.x] = s;
    }
    __syncthreads();
    if (threadIdx.x == 0) {
        unsigned cum = 0;
        int seg = 0;
        for (; seg < 32; ++seg) {
            if (cum + part[seg] >= r) break;
            cum += part[seg];
        }
        int i = seg * 32;
        for (;; ++i) {
            if (cum + h[i] >= r) break;
            cum += h[i];
        }
        sstate[2] = (unsigned)i;
        sstate[3] = r - cum;
    }
    __syncthreads();
    unsigned b1 = sstate[2];
    r = sstate[3];

    // level 2: bits 9..0
    h[threadIdx.x] = 0;
    __syncthreads();
    for (unsigned i = threadIdx.x; i < m; i += blockDim.x) {
        unsigned u = cand[i];
        if (((u >> 10) & 1023u) == b1) atomicAdd(&h[u & 1023u], 1u);
    }
    __syncthreads();
    if (threadIdx.x < 32) {
        unsigned s = 0;
        for (int j = 0; j < 32; ++j) s += h[threadIdx.x * 32 + j];
        part[threadIdx.x] = s;
    }
    __syncthreads();
    if (threadIdx.x == 0) {
        unsigned cum = 0;
        int seg = 0;
        for (; seg < 32; ++seg) {
            if (cum + part[seg] >= r) break;
            cum += part[seg];
        }
        int i = seg * 32;
        for (;; ++i) {
            if (cum + h[i] >= r) break;
            cum += h[i];
        }
        unsigned bits = (bsel << 20) | (b1 << 10) | (unsigned)i;
        float maxcur = __uint_as_float(bits);
        unsigned mk = *minkey;
        float mincur = (mk & 0x80000000u) ? __uint_as_float(mk & 0x7FFFFFFFu)
                                          : __uint_as_float(~mk);
        bool first = (*num_flag == 0);
        float nmax = first ? maxcur : (0.9f * max_val[0] + 0.1f * maxcur);
        float nmin = first ? mincur : (0.9f * min_val[0] + 0.1f * mincur);
        out[0] = nmin;
        out[1] = nmax;
    }
}

extern "C" void kernel_launch(void* const* d_in, const int* in_sizes, int n_in,
                              void* d_out, int out_size, void* d_ws, size_t ws_size,
                              hipStream_t stream) {
    const float* in = (const float*)d_in[0];
    const float* minv = (const float*)d_in[1];
    const float* maxv = (const float*)d_in[2];
    const int* flag = (const int*)d_in[3];
    float* out = (float*)d_out;

    long long n = (long long)in_sizes[0];
    // k = int(0.9999 * n), matching Python's double arithmetic + truncation
    unsigned k = (unsigned)(long long)(0.9999 * (double)n);
    unsigned* ws = (unsigned*)d_ws;

    void* args[] = {(void*)&in, (void*)&n, (void*)&k,
                    (void*)&minv, (void*)&maxv, (void*)&flag,
                    (void*)&ws, (void*)&out};
    hipLaunchCooperativeKernel((const void*)fused_kernel,
                               dim3(NBLOCKS), dim3(NTHREADS),
                               args, 0, stream);
}

// Round 4
// 267.567 us; speedup vs baseline: 1.2850x; 1.2850x over previous
//
#include <hip/hip_runtime.h>
#include <stdint.h>
#include <float.h>

#define NBINS 2048
#define NC 8            // LDS histogram copies, bin-interleaved (64 KB)
#define CAND_CAP 32768
#define NBLOCKS 512
#define NTHREADS 1024

// ws layout (unsigned):
// [0, 2048)  coarse histogram (top 11 bits of abs bits)
// [2048]     candidate counter
// [2049]     inv_minkey: max over ~fkey(x), init 0  (so one memset(0) suffices)
// [2064, +CAND_CAP) candidate abs-bit patterns

__device__ __forceinline__ unsigned fkey(float f) {
    unsigned u = __float_as_uint(f);
    return (u & 0x80000000u) ? ~u : (u | 0x80000000u);
}

// 2 blocks/CU (8 waves/EU) -> 32 waves/CU, VGPR capped at 64.
__global__ __launch_bounds__(NTHREADS, 8) void histmin_kernel(
    const float* __restrict__ in, long long n,
    unsigned* __restrict__ hist, unsigned* __restrict__ inv_minkey) {
    __shared__ unsigned h[NBINS * NC];
    for (int i = threadIdx.x; i < NBINS * NC; i += blockDim.x) h[i] = 0;
    __syncthreads();

    const unsigned c = threadIdx.x & (NC - 1);
    long long gtid = (long long)blockIdx.x * blockDim.x + threadIdx.x;
    long long gs = (long long)gridDim.x * blockDim.x;
    const float4* in4 = (const float4*)in;
    long long n4 = n >> 2;

    float mn = FLT_MAX;
    // 4x unrolled grid-stride: 4 independent float4 loads in flight per wave
    long long i = gtid;
    for (; i + 3 * gs < n4; i += 4 * gs) {
        float4 v0 = in4[i];
        float4 v1 = in4[i + gs];
        float4 v2 = in4[i + 2 * gs];
        float4 v3 = in4[i + 3 * gs];
#pragma unroll
        for (int j = 0; j < 4; ++j) {
            float4 v = (j == 0) ? v0 : (j == 1) ? v1 : (j == 2) ? v2 : v3;
            mn = fminf(mn, fminf(fminf(v.x, v.y), fminf(v.z, v.w)));
            atomicAdd(&h[((__float_as_uint(v.x) & 0x7FFFFFFFu) >> 20) * NC + c], 1u);
            atomicAdd(&h[((__float_as_uint(v.y) & 0x7FFFFFFFu) >> 20) * NC + c], 1u);
            atomicAdd(&h[((__float_as_uint(v.z) & 0x7FFFFFFFu) >> 20) * NC + c], 1u);
            atomicAdd(&h[((__float_as_uint(v.w) & 0x7FFFFFFFu) >> 20) * NC + c], 1u);
        }
    }
    for (; i < n4; i += gs) {
        float4 v = in4[i];
        mn = fminf(mn, fminf(fminf(v.x, v.y), fminf(v.z, v.w)));
        atomicAdd(&h[((__float_as_uint(v.x) & 0x7FFFFFFFu) >> 20) * NC + c], 1u);
        atomicAdd(&h[((__float_as_uint(v.y) & 0x7FFFFFFFu) >> 20) * NC + c], 1u);
        atomicAdd(&h[((__float_as_uint(v.z) & 0x7FFFFFFFu) >> 20) * NC + c], 1u);
        atomicAdd(&h[((__float_as_uint(v.w) & 0x7FFFFFFFu) >> 20) * NC + c], 1u);
    }
    for (long long t = (n4 << 2) + gtid; t < n; t += gs) {
        float v = in[t];
        mn = fminf(mn, v);
        atomicAdd(&h[((__float_as_uint(v) & 0x7FFFFFFFu) >> 20) * NC + c], 1u);
    }
    __syncthreads();

    for (int b = threadIdx.x; b < NBINS; b += blockDim.x) {
        unsigned s = 0;
#pragma unroll
        for (int j = 0; j < NC; ++j) s += h[b * NC + j];
        if (s) atomicAdd(&hist[b], s);
    }

    // block min reduce via inverted key (identity 0 -> single memset covers it)
    unsigned ik = ~fkey(mn);
    for (int off = 32; off > 0; off >>= 1)
        ik = max(ik, (unsigned)__shfl_down((int)ik, off));
    __shared__ unsigned wmax[NTHREADS / 64];
    if ((threadIdx.x & 63) == 0) wmax[threadIdx.x >> 6] = ik;
    __syncthreads();
    if (threadIdx.x == 0) {
        unsigned m = wmax[0];
        for (int w = 1; w < NTHREADS / 64; ++w) m = max(m, wmax[w]);
        atomicMax(inv_minkey, m);
    }
}

// Every block redundantly computes the selected bucket from hist (cheap),
// then compacts matching elements. No separate select kernel.
__device__ __forceinline__ void select_bucket(const unsigned* hist, unsigned k,
                                              unsigned* smem, unsigned* outb) {
    if (threadIdx.x < 256) {
        unsigned s = 0;
        for (int j = 0; j < 8; ++j) s += hist[threadIdx.x * 8 + j];
        smem[threadIdx.x] = s;
    }
    __syncthreads();
    if (threadIdx.x == 0) {
        unsigned cum = 0;
        int seg = 0;
        for (; seg < 256; ++seg) {
            if (cum + smem[seg] >= k) break;
            cum += smem[seg];
        }
        int b = seg * 8;
        for (;; ++b) {
            unsigned cc = hist[b];
            if (cum + cc >= k) break;
            cum += cc;
        }
        outb[0] = (unsigned)b;
        outb[1] = k - cum;  // 1-indexed residual rank
    }
    __syncthreads();
}

__global__ __launch_bounds__(NTHREADS, 8) void compact_kernel(
    const float* __restrict__ in, long long n, unsigned k,
    const unsigned* __restrict__ hist, unsigned* __restrict__ counter,
    unsigned* __restrict__ cand) {
    __shared__ unsigned smem[256];
    __shared__ unsigned bsel[2];
    select_bucket(hist, k, smem, bsel);
    unsigned b = bsel[0];

    long long gtid = (long long)blockIdx.x * blockDim.x + threadIdx.x;
    long long gs = (long long)gridDim.x * blockDim.x;
    const float4* in4 = (const float4*)in;
    long long n4 = n >> 2;

    long long i = gtid;
    for (; i + gs < n4; i += 2 * gs) {
        float4 v0 = in4[i];
        float4 v1 = in4[i + gs];
        unsigned u[8];
        u[0] = __float_as_uint(v0.x) & 0x7FFFFFFFu;
        u[1] = __float_as_uint(v0.y) & 0x7FFFFFFFu;
        u[2] = __float_as_uint(v0.z) & 0x7FFFFFFFu;
        u[3] = __float_as_uint(v0.w) & 0x7FFFFFFFu;
        u[4] = __float_as_uint(v1.x) & 0x7FFFFFFFu;
        u[5] = __float_as_uint(v1.y) & 0x7FFFFFFFu;
        u[6] = __float_as_uint(v1.z) & 0x7FFFFFFFu;
        u[7] = __float_as_uint(v1.w) & 0x7FFFFFFFu;
#pragma unroll
        for (int j = 0; j < 8; ++j) {
            if ((u[j] >> 20) == b) {
                unsigned p = atomicAdd(counter, 1u);
                if (p < CAND_CAP) cand[p] = u[j];
            }
        }
    }
    for (; i < n4; i += gs) {
        float4 v = in4[i];
        unsigned u[4];
        u[0] = __float_as_uint(v.x) & 0x7FFFFFFFu;
        u[1] = __float_as_uint(v.y) & 0x7FFFFFFFu;
        u[2] = __float_as_uint(v.z) & 0x7FFFFFFFu;
        u[3] = __float_as_uint(v.w) & 0x7FFFFFFFu;
#pragma unroll
        for (int j = 0; j < 4; ++j) {
            if ((u[j] >> 20) == b) {
                unsigned p = atomicAdd(counter, 1u);
                if (p < CAND_CAP) cand[p] = u[j];
            }
        }
    }
    for (long long t = (n4 << 2) + gtid; t < n; t += gs) {
        unsigned u = __float_as_uint(in[t]) & 0x7FFFFFFFu;
        if ((u >> 20) == b) {
            unsigned p = atomicAdd(counter, 1u);
            if (p < CAND_CAP) cand[p] = u;
        }
    }
}

__global__ __launch_bounds__(1024) void final_kernel(
    const unsigned* __restrict__ hist, unsigned k,
    const unsigned* __restrict__ cand, const unsigned* __restrict__ counterp,
    const unsigned* __restrict__ inv_minkey,
    const float* __restrict__ min_val, const float* __restrict__ max_val,
    const int* __restrict__ num_flag, float* __restrict__ out) {
    __shared__ unsigned h[1024];
    __shared__ unsigned part[256];
    __shared__ unsigned bsel[2];
    __shared__ unsigned st[2];

    select_bucket(hist, k, part, bsel);
    unsigned b = bsel[0];
    unsigned r = bsel[1];
    unsigned m = min(*counterp, (unsigned)CAND_CAP);

    // level 1: bits 19..10
    h[threadIdx.x] = 0;
    __syncthreads();
    for (unsigned i = threadIdx.x; i < m; i += blockDim.x)
        atomicAdd(&h[(cand[i] >> 10) & 1023u], 1u);
    __syncthreads();
    if (threadIdx.x < 32) {
        unsigned s = 0;
        for (int j = 0; j < 32; ++j) s += h[threadIdx.x * 32 + j];
        part[threadIdx.x] = s;
    }
    __syncthreads();
    if (threadIdx.x == 0) {
        unsigned cum = 0;
        int seg = 0;
        for (; seg < 32; ++seg) {
            if (cum + part[seg] >= r) break;
            cum += part[seg];
        }
        int i = seg * 32;
        for (;; ++i) {
            if (cum + h[i] >= r) break;
            cum += h[i];
        }
        st[0] = (unsigned)i;
        st[1] = r - cum;
    }
    __syncthreads();
    unsigned b1 = st[0];
    r = st[1];

    // level 2: bits 9..0
    h[threadIdx.x] = 0;
    __syncthreads();
    for (unsigned i = threadIdx.x; i < m; i += blockDim.x) {
        unsigned u = cand[i];
        if (((u >> 10) & 1023u) == b1) atomicAdd(&h[u & 1023u], 1u);
    }
    __syncthreads();
    if (threadIdx.x < 32) {
        unsigned s = 0;
        for (int j = 0; j < 32; ++j) s += h[threadIdx.x * 32 + j];
        part[threadIdx.x] = s;
    }
    __syncthreads();
    if (threadIdx.x == 0) {
        unsigned cum = 0;
        int seg = 0;
        for (; seg < 32; ++seg) {
            if (cum + part[seg] >= r) break;
            cum += part[seg];
        }
        int i = seg * 32;
        for (;; ++i) {
            if (cum + h[i] >= r) break;
            cum += h[i];
        }
        unsigned bits = (b << 20) | (b1 << 10) | (unsigned)i;
        float maxcur = __uint_as_float(bits);
        unsigned mk = ~(*inv_minkey);
        float mincur = (mk & 0x80000000u) ? __uint_as_float(mk & 0x7FFFFFFFu)
                                          : __uint_as_float(~mk);
        bool first = (*num_flag == 0);
        float nmax = first ? maxcur : (0.9f * max_val[0] + 0.1f * maxcur);
        float nmin = first ? mincur : (0.9f * min_val[0] + 0.1f * mincur);
        out[0] = nmin;
        out[1] = nmax;
    }
}

extern "C" void kernel_launch(void* const* d_in, const int* in_sizes, int n_in,
                              void* d_out, int out_size, void* d_ws, size_t ws_size,
                              hipStream_t stream) {
    const float* in = (const float*)d_in[0];
    const float* minv = (const float*)d_in[1];
    const float* maxv = (const float*)d_in[2];
    const int* flag = (const int*)d_in[3];
    float* out = (float*)d_out;

    long long n = (long long)in_sizes[0];
    // k = int(0.9999 * n), matching Python's double arithmetic + truncation
    unsigned k = (unsigned)(long long)(0.9999 * (double)n);

    unsigned* ws = (unsigned*)d_ws;
    unsigned* hist = ws;            // 2048
    unsigned* counter = ws + 2048;  // 1
    unsigned* inv_minkey = ws + 2049;
    unsigned* cand = ws + 2064;     // CAND_CAP

    hipMemsetAsync(ws, 0, 2064 * sizeof(unsigned), stream);

    histmin_kernel<<<NBLOCKS, NTHREADS, 0, stream>>>(in, n, hist, inv_minkey);
    compact_kernel<<<NBLOCKS, NTHREADS, 0, stream>>>(in, n, k, hist, counter, cand);
    final_kernel<<<1, 1024, 0, stream>>>(hist, k, cand, counter, inv_minkey,
                                         minv, maxv, flag, out);
}